// Round 1
// baseline (366.078 us; speedup 1.0000x reference)
//
#include <hip/hip_runtime.h>
#include <hip/hip_bf16.h>
#include <math.h>

// QuantumFFN: out[m,n] = sum_k relu(sum_q cos(x[m,q])cos(theta[q]) * W1[k,q]) * W2[n,k]
// M=16384 (B*S), N=1024 (embed D), K=4096 (ffn F), Q=8.
// Fused single kernel: A-tile (h) generated in-block, B-tile = W2 (BT layout) cvt to bf16.

using f32x4  = __attribute__((ext_vector_type(4))) float;
using bf16x8 = __attribute__((ext_vector_type(8))) short;
using i32x4  = __attribute__((ext_vector_type(4))) int;
using u32x2  = __attribute__((ext_vector_type(2))) unsigned int;

#define MT 16384
#define NT 1024
#define KT 4096
#define BM 128
#define BN 128
#define BK 64

static __device__ inline unsigned short f2bf(float f) {
    __hip_bfloat16 b = __float2bfloat16(f);
    unsigned short u;
    __builtin_memcpy(&u, &b, 2);
    return u;
}

__global__ __launch_bounds__(256, 3)
void qffn_fused(const float* __restrict__ x, const float* __restrict__ theta,
                const float* __restrict__ W1, const float* __restrict__ W2,
                float* __restrict__ out)
{
    __shared__ __align__(16) unsigned short sA[BM * BK]; // 16 KB, XOR-swizzled
    __shared__ __align__(16) unsigned short sB[BN * BK]; // 16 KB, XOR-swizzled

    const int tid  = threadIdx.x;
    const int lane = tid & 63;
    const int wave = tid >> 6;
    const int m0 = blockIdx.x * BM;
    const int n0 = blockIdx.y * BN;

    // ---- per-thread z row: token (m0 + arow), 8 f32 in registers (hoisted out of K-loop)
    const int arow = tid & 127;
    float zc[8];
    {
        const float* xp = x + (size_t)(m0 + arow) * 1024;
        f32x4 x0 = *reinterpret_cast<const f32x4*>(xp);
        f32x4 x1 = *reinterpret_cast<const f32x4*>(xp + 4);
        #pragma unroll
        for (int q = 0; q < 4; ++q) {
            zc[q]     = cosf(x0[q]) * cosf(theta[q]);
            zc[q + 4] = cosf(x1[q]) * cosf(theta[q + 4]);
        }
    }

    f32x4 acc[4][4];
    #pragma unroll
    for (int i = 0; i < 4; ++i)
        #pragma unroll
        for (int j = 0; j < 4; ++j)
            acc[i][j] = {0.f, 0.f, 0.f, 0.f};

    const int wr  = (wave >> 1) * 64;   // wave output row offset in tile
    const int wc  = (wave & 1) * 64;    // wave output col offset in tile
    const int l16 = lane & 15;
    const int lk8 = (lane >> 4) * 8;    // k sub-offset within fragment

    for (int k0 = 0; k0 < KT; k0 += BK) {
        // ---- stage A: h[arow][0..63] = relu(z . W1) -> bf16, swizzled LDS
        #pragma unroll
        for (int g = 0; g < 4; ++g) {
            const int cg  = (tid >> 7) + 2 * g;               // wave-uniform col-group 0..7
            const int cgu = __builtin_amdgcn_readfirstlane(cg);
            const float* w1p = W1 + (size_t)(k0 + cgu * 8) * 8; // 64 consecutive f32 (scalar loads)
            i32x4 pk;
            #pragma unroll
            for (int p = 0; p < 4; ++p) {
                float h0 = 0.f, h1 = 0.f;
                #pragma unroll
                for (int q = 0; q < 8; ++q) {
                    h0 = fmaf(zc[q], w1p[(2 * p) * 8 + q], h0);
                    h1 = fmaf(zc[q], w1p[(2 * p + 1) * 8 + q], h1);
                }
                pk[p] = (int)(((unsigned)f2bf(fmaxf(h0, 0.f))) |
                              (((unsigned)f2bf(fmaxf(h1, 0.f))) << 16));
            }
            const int off = (arow * 64 + cg * 8) ^ ((arow & 7) << 3);
            *reinterpret_cast<i32x4*>(&sA[off]) = pk;
        }

        // ---- stage B: W2[n0+row][k0..k0+63] f32 -> bf16, swizzled LDS
        {
            const int fi = tid & 15;   // float4 index along k
            const int rb = tid >> 4;   // row base 0..15
            #pragma unroll
            for (int r = 0; r < 8; ++r) {
                const int row = rb + r * 16;
                f32x4 v = *(reinterpret_cast<const f32x4*>(W2 + (size_t)(n0 + row) * KT + k0) + fi);
                u32x2 pk;
                pk[0] = (unsigned)f2bf(v[0]) | ((unsigned)f2bf(v[1]) << 16);
                pk[1] = (unsigned)f2bf(v[2]) | ((unsigned)f2bf(v[3]) << 16);
                const int off = (row * 64 + fi * 4) ^ ((row & 7) << 3);
                *reinterpret_cast<u32x2*>(&sB[off]) = pk;
            }
        }
        __syncthreads();

        // ---- MFMA: 2 k-substeps of 32
        #pragma unroll
        for (int s = 0; s < 2; ++s) {
            bf16x8 af[4], bfr[4];
            #pragma unroll
            for (int i = 0; i < 4; ++i) {
                const int row = wr + i * 16 + l16;
                const int off = (row * 64 + s * 32 + lk8) ^ ((row & 7) << 3);
                af[i] = *reinterpret_cast<const bf16x8*>(&sA[off]);
            }
            #pragma unroll
            for (int j = 0; j < 4; ++j) {
                const int row = wc + j * 16 + l16;
                const int off = (row * 64 + s * 32 + lk8) ^ ((row & 7) << 3);
                bfr[j] = *reinterpret_cast<const bf16x8*>(&sB[off]);
            }
            #pragma unroll
            for (int i = 0; i < 4; ++i)
                #pragma unroll
                for (int j = 0; j < 4; ++j)
                    acc[i][j] = __builtin_amdgcn_mfma_f32_16x16x32_bf16(af[i], bfr[j], acc[i][j], 0, 0, 0);
        }
        __syncthreads();
    }

    // ---- epilogue: C/D layout col=lane&15, row=(lane>>4)*4+reg
    const int orow0 = m0 + wr + (lane >> 4) * 4;
    const int ocol0 = n0 + wc + l16;
    #pragma unroll
    for (int i = 0; i < 4; ++i)
        #pragma unroll
        for (int j = 0; j < 4; ++j)
            #pragma unroll
            for (int jj = 0; jj < 4; ++jj)
                out[(size_t)(orow0 + i * 16 + jj) * NT + (ocol0 + j * 16)] = acc[i][j][jj];
}

extern "C" void kernel_launch(void* const* d_in, const int* in_sizes, int n_in,
                              void* d_out, int out_size, void* d_ws, size_t ws_size,
                              hipStream_t stream) {
    const float* x     = (const float*)d_in[0];
    const float* theta = (const float*)d_in[1];
    const float* W1    = (const float*)d_in[2];
    const float* W2    = (const float*)d_in[3];
    float* out = (float*)d_out;

    dim3 grid(MT / BM, NT / BN);  // 128 x 8
    qffn_fused<<<grid, dim3(256, 1, 1), 0, stream>>>(x, theta, W1, W2, out);
}

// Round 2
// 173.963 us; speedup vs baseline: 2.1043x; 2.1043x over previous
//
#include <hip/hip_runtime.h>
#include <hip/hip_bf16.h>
#include <math.h>

// QuantumFFN: out[m,n] = sum_k relu(sum_q cos(x[m,q])cos(theta[q]) * W1[k,q]) * W2[n,k]
// M=16384 (B*S), N=1024 (embed D), K=4096 (ffn F), Q=8.
//
// Two-pass: (1) materialize h (bf16) and W2 (bf16) into d_ws in a tiled,
// XOR-swizzled layout; (2) bf16 MFMA GEMM with global_load_lds staging.
// Falls back to the fused single-kernel path if ws_size is insufficient.

using f32x4  = __attribute__((ext_vector_type(4))) float;
using bf16x8 = __attribute__((ext_vector_type(8))) short;
using i32x4  = __attribute__((ext_vector_type(4))) int;
using u32x2  = __attribute__((ext_vector_type(2))) unsigned int;

#define M_TOT 16384
#define N_TOT 1024
#define K_TOT 4096
#define BM 128
#define BN 128
#define BK 64

// ws layout: h tiled [128 mt][64 kt][128 row][64 k] bf16  (128 MiB)
//            w2 tiled [8 nt][64 kt][128 row][64 k] bf16   (8 MiB)
//            z [16384][8] f32                             (512 KiB)
static const size_t H_BYTES   = (size_t)M_TOT * K_TOT * 2;
static const size_t W2B_BYTES = (size_t)N_TOT * K_TOT * 2;
static const size_t Z_BYTES   = (size_t)M_TOT * 8 * 4;
static const size_t WS_NEED   = H_BYTES + W2B_BYTES + Z_BYTES;

#define TILE_BYTES (128 * 64 * 2)
#define SWZ(row, bytecol) ((bytecol) ^ (((row) & 7) << 4))

#define GLD16(gp, lp) __builtin_amdgcn_global_load_lds( \
    (const __attribute__((address_space(1))) unsigned int*)(const void*)(gp), \
    (__attribute__((address_space(3))) unsigned int*)(void*)(lp), 16, 0, 0)

static __device__ inline unsigned short f2bf(float f) {
    __hip_bfloat16 b = __float2bfloat16(f);
    unsigned short u;
    __builtin_memcpy(&u, &b, 2);
    return u;
}

// ---------------- pass 1a: z[m][q] = cos(x[m,q]) * cos(theta[q]) ----------------
__global__ __launch_bounds__(256)
void k_z(const float* __restrict__ x, const float* __restrict__ theta,
         float* __restrict__ z)
{
    const int m = blockIdx.x * 256 + threadIdx.x;
    const float* xp = x + (size_t)m * 1024;
    f32x4 a = *reinterpret_cast<const f32x4*>(xp);
    f32x4 b = *reinterpret_cast<const f32x4*>(xp + 4);
    f32x4 o0, o1;
    #pragma unroll
    for (int q = 0; q < 4; ++q) {
        o0[q] = cosf(a[q]) * cosf(theta[q]);
        o1[q] = cosf(b[q]) * cosf(theta[q + 4]);
    }
    *reinterpret_cast<f32x4*>(z + (size_t)m * 8)     = o0;
    *reinterpret_cast<f32x4*>(z + (size_t)m * 8 + 4) = o1;
}

// ---------------- pass 1b: h = relu(z . W1) -> bf16 tiled-swizzled ----------------
// block: 128 m-rows (bx) x 128 k-cols (by). thread: 8 m x 8 k register tile.
__global__ __launch_bounds__(256)
void k_h(const float* __restrict__ z, const float* __restrict__ W1,
         unsigned short* __restrict__ hws)
{
    __shared__ float sZ[128 * 8];
    __shared__ float sW[128 * 8];
    const int bx = blockIdx.x;   // m-tile 0..127
    const int by = blockIdx.y;   // k-chunk 0..31 (128 k each)
    const int tid = threadIdx.x;

    *reinterpret_cast<f32x4*>(&sZ[tid * 4]) =
        *reinterpret_cast<const f32x4*>(z + (size_t)bx * 1024 + tid * 4);
    *reinterpret_cast<f32x4*>(&sW[tid * 4]) =
        *reinterpret_cast<const f32x4*>(W1 + (size_t)by * 1024 + tid * 4);
    __syncthreads();

    const int tm = tid >> 4;     // 0..15 -> m rows tm*8..tm*8+7
    const int tk = tid & 15;     // 0..15 -> k cols tk*8..tk*8+7

    f32x4 w1a[8], w1b[8];
    #pragma unroll
    for (int kk = 0; kk < 8; ++kk) {
        w1a[kk] = *reinterpret_cast<const f32x4*>(&sW[(tk * 8 + kk) * 8]);
        w1b[kk] = *reinterpret_cast<const f32x4*>(&sW[(tk * 8 + kk) * 8 + 4]);
    }

    const int kt    = by * 2 + (tk >> 3);       // global k-tile index
    const int kcolb = (tk & 7) * 16;            // byte col within tile row
    unsigned short* tbase = hws + ((size_t)bx * 64 + kt) * (TILE_BYTES / 2);

    #pragma unroll
    for (int i = 0; i < 8; ++i) {
        const int row = tm * 8 + i;
        f32x4 za = *reinterpret_cast<const f32x4*>(&sZ[row * 8]);
        f32x4 zb = *reinterpret_cast<const f32x4*>(&sZ[row * 8 + 4]);
        unsigned hu[8];
        #pragma unroll
        for (int kk = 0; kk < 8; ++kk) {
            float h = 0.f;
            #pragma unroll
            for (int q = 0; q < 4; ++q) {
                h = fmaf(za[q], w1a[kk][q], h);
                h = fmaf(zb[q], w1b[kk][q], h);
            }
            hu[kk] = (unsigned)f2bf(fmaxf(h, 0.f));
        }
        i32x4 pk;
        pk[0] = (int)(hu[0] | (hu[1] << 16));
        pk[1] = (int)(hu[2] | (hu[3] << 16));
        pk[2] = (int)(hu[4] | (hu[5] << 16));
        pk[3] = (int)(hu[6] | (hu[7] << 16));
        char* dst = (char*)tbase + row * 128 + SWZ(row, kcolb);
        *reinterpret_cast<i32x4*>(dst) = pk;
    }
}

// ---------------- pass 1c: W2 f32 -> bf16 tiled-swizzled ----------------
__global__ __launch_bounds__(256)
void k_w2(const float* __restrict__ W2, unsigned short* __restrict__ w2ws)
{
    const int gt = blockIdx.x * 256 + threadIdx.x;   // one 16B unit (8 k) each
    const int n  = gt >> 9;                          // 512 units per row
    const int k8 = gt & 511;
    const float* p = W2 + (size_t)n * K_TOT + k8 * 8;
    f32x4 a = *reinterpret_cast<const f32x4*>(p);
    f32x4 b = *reinterpret_cast<const f32x4*>(p + 4);
    i32x4 pk;
    pk[0] = (int)((unsigned)f2bf(a[0]) | ((unsigned)f2bf(a[1]) << 16));
    pk[1] = (int)((unsigned)f2bf(a[2]) | ((unsigned)f2bf(a[3]) << 16));
    pk[2] = (int)((unsigned)f2bf(b[0]) | ((unsigned)f2bf(b[1]) << 16));
    pk[3] = (int)((unsigned)f2bf(b[2]) | ((unsigned)f2bf(b[3]) << 16));
    const int nt = n >> 7, row = n & 127, kt = k8 >> 3, kcolb = (k8 & 7) * 16;
    char* dst = (char*)(w2ws + ((size_t)nt * 64 + kt) * (TILE_BYTES / 2))
              + row * 128 + SWZ(row, kcolb);
    *reinterpret_cast<i32x4*>(dst) = pk;
}

// ---------------- pass 2: out = h @ W2^T  (bf16 MFMA, m97 structure) ----------------
__global__ __launch_bounds__(256, 4)
void k_gemm(const unsigned short* __restrict__ hws,
            const unsigned short* __restrict__ w2ws,
            float* __restrict__ out)
{
    __shared__ __align__(16) unsigned short sA[BM * BK];
    __shared__ __align__(16) unsigned short sB[BN * BK];

    const int tid  = threadIdx.x;
    const int lane = tid & 63;
    const int wave = tid >> 6;
    const int mt = blockIdx.x;
    const int nt = blockIdx.y;

    const char* atile0 = (const char*)hws  + (size_t)mt * 64 * TILE_BYTES;
    const char* btile0 = (const char*)w2ws + (size_t)nt * 64 * TILE_BYTES;

    f32x4 acc[4][4];
    #pragma unroll
    for (int i = 0; i < 4; ++i)
        #pragma unroll
        for (int j = 0; j < 4; ++j)
            acc[i][j] = {0.f, 0.f, 0.f, 0.f};

    const int wr   = (wave >> 1) * 64;
    const int wc   = (wave & 1) * 64;
    const int l16  = lane & 15;
    const int lk8b = (lane >> 4) * 16;          // k byte sub-offset in fragment
    const int ou   = wave * 1024 + lane * 16;   // staging offset (global side)
    const int ol   = wave * 1024;               // staging offset (lds side, wave-uniform)

    for (int ks = 0; ks < 64; ++ks) {
        const char* ga = atile0 + (size_t)ks * TILE_BYTES;
        const char* gb = btile0 + (size_t)ks * TILE_BYTES;
        #pragma unroll
        for (int c = 0; c < 4; ++c)
            GLD16(ga + c * 4096 + ou, (char*)sA + c * 4096 + ol);
        #pragma unroll
        for (int c = 0; c < 4; ++c)
            GLD16(gb + c * 4096 + ou, (char*)sB + c * 4096 + ol);
        __syncthreads();

        #pragma unroll
        for (int s = 0; s < 2; ++s) {
            bf16x8 af[4], bfr[4];
            #pragma unroll
            for (int i = 0; i < 4; ++i) {
                const int row = wr + i * 16 + l16;
                af[i] = *reinterpret_cast<const bf16x8*>(
                    (const char*)sA + row * 128 + SWZ(row, s * 64 + lk8b));
            }
            #pragma unroll
            for (int j = 0; j < 4; ++j) {
                const int row = wc + j * 16 + l16;
                bfr[j] = *reinterpret_cast<const bf16x8*>(
                    (const char*)sB + row * 128 + SWZ(row, s * 64 + lk8b));
            }
            #pragma unroll
            for (int i = 0; i < 4; ++i)
                #pragma unroll
                for (int j = 0; j < 4; ++j)
                    acc[i][j] = __builtin_amdgcn_mfma_f32_16x16x32_bf16(af[i], bfr[j], acc[i][j], 0, 0, 0);
        }
        __syncthreads();
    }

    const int orow0 = mt * BM + wr + (lane >> 4) * 4;
    const int ocol0 = nt * BN + wc + l16;
    #pragma unroll
    for (int i = 0; i < 4; ++i)
        #pragma unroll
        for (int j = 0; j < 4; ++j)
            #pragma unroll
            for (int jj = 0; jj < 4; ++jj)
                out[(size_t)(orow0 + i * 16 + jj) * N_TOT + (ocol0 + j * 16)] = acc[i][j][jj];
}

// ---------------- fallback: round-1 fused kernel (used only if ws too small) ----------------
__global__ __launch_bounds__(256, 3)
void qffn_fused(const float* __restrict__ x, const float* __restrict__ theta,
                const float* __restrict__ W1, const float* __restrict__ W2,
                float* __restrict__ out)
{
    __shared__ __align__(16) unsigned short sA[BM * BK];
    __shared__ __align__(16) unsigned short sB[BN * BK];

    const int tid  = threadIdx.x;
    const int lane = tid & 63;
    const int wave = tid >> 6;
    const int m0 = blockIdx.x * BM;
    const int n0 = blockIdx.y * BN;

    const int arow = tid & 127;
    float zc[8];
    {
        const float* xp = x + (size_t)(m0 + arow) * 1024;
        f32x4 x0 = *reinterpret_cast<const f32x4*>(xp);
        f32x4 x1 = *reinterpret_cast<const f32x4*>(xp + 4);
        #pragma unroll
        for (int q = 0; q < 4; ++q) {
            zc[q]     = cosf(x0[q]) * cosf(theta[q]);
            zc[q + 4] = cosf(x1[q]) * cosf(theta[q + 4]);
        }
    }

    f32x4 acc[4][4];
    #pragma unroll
    for (int i = 0; i < 4; ++i)
        #pragma unroll
        for (int j = 0; j < 4; ++j)
            acc[i][j] = {0.f, 0.f, 0.f, 0.f};

    const int wr  = (wave >> 1) * 64;
    const int wc  = (wave & 1) * 64;
    const int l16 = lane & 15;
    const int lk8 = (lane >> 4) * 8;

    for (int k0 = 0; k0 < K_TOT; k0 += BK) {
        #pragma unroll
        for (int g = 0; g < 4; ++g) {
            const int cg  = (tid >> 7) + 2 * g;
            const int cgu = __builtin_amdgcn_readfirstlane(cg);
            const float* w1p = W1 + (size_t)(k0 + cgu * 8) * 8;
            i32x4 pk;
            #pragma unroll
            for (int p = 0; p < 4; ++p) {
                float h0 = 0.f, h1 = 0.f;
                #pragma unroll
                for (int q = 0; q < 8; ++q) {
                    h0 = fmaf(zc[q], w1p[(2 * p) * 8 + q], h0);
                    h1 = fmaf(zc[q], w1p[(2 * p + 1) * 8 + q], h1);
                }
                pk[p] = (int)(((unsigned)f2bf(fmaxf(h0, 0.f))) |
                              (((unsigned)f2bf(fmaxf(h1, 0.f))) << 16));
            }
            const int off = (arow * 64 + cg * 8) ^ ((arow & 7) << 3);
            *reinterpret_cast<i32x4*>(&sA[off]) = pk;
        }
        {
            const int fi = tid & 15;
            const int rb = tid >> 4;
            #pragma unroll
            for (int r = 0; r < 8; ++r) {
                const int row = rb + r * 16;
                f32x4 v = *(reinterpret_cast<const f32x4*>(W2 + (size_t)(n0 + row) * K_TOT + k0) + fi);
                u32x2 pk;
                pk[0] = (unsigned)f2bf(v[0]) | ((unsigned)f2bf(v[1]) << 16);
                pk[1] = (unsigned)f2bf(v[2]) | ((unsigned)f2bf(v[3]) << 16);
                const int off = (row * 64 + fi * 4) ^ ((row & 7) << 3);
                *reinterpret_cast<u32x2*>(&sB[off]) = pk;
            }
        }
        __syncthreads();

        #pragma unroll
        for (int s = 0; s < 2; ++s) {
            bf16x8 af[4], bfr[4];
            #pragma unroll
            for (int i = 0; i < 4; ++i) {
                const int row = wr + i * 16 + l16;
                const int off = (row * 64 + s * 32 + lk8) ^ ((row & 7) << 3);
                af[i] = *reinterpret_cast<const bf16x8*>(&sA[off]);
            }
            #pragma unroll
            for (int j = 0; j < 4; ++j) {
                const int row = wc + j * 16 + l16;
                const int off = (row * 64 + s * 32 + lk8) ^ ((row & 7) << 3);
                bfr[j] = *reinterpret_cast<const bf16x8*>(&sB[off]);
            }
            #pragma unroll
            for (int i = 0; i < 4; ++i)
                #pragma unroll
                for (int j = 0; j < 4; ++j)
                    acc[i][j] = __builtin_amdgcn_mfma_f32_16x16x32_bf16(af[i], bfr[j], acc[i][j], 0, 0, 0);
        }
        __syncthreads();
    }

    const int orow0 = m0 + wr + (lane >> 4) * 4;
    const int ocol0 = n0 + wc + l16;
    #pragma unroll
    for (int i = 0; i < 4; ++i)
        #pragma unroll
        for (int j = 0; j < 4; ++j)
            #pragma unroll
            for (int jj = 0; jj < 4; ++jj)
                out[(size_t)(orow0 + i * 16 + jj) * N_TOT + (ocol0 + j * 16)] = acc[i][j][jj];
}

extern "C" void kernel_launch(void* const* d_in, const int* in_sizes, int n_in,
                              void* d_out, int out_size, void* d_ws, size_t ws_size,
                              hipStream_t stream) {
    const float* x     = (const float*)d_in[0];
    const float* theta = (const float*)d_in[1];
    const float* W1    = (const float*)d_in[2];
    const float* W2    = (const float*)d_in[3];
    float* out = (float*)d_out;

    if (ws_size >= WS_NEED) {
        unsigned short* hws  = (unsigned short*)d_ws;
        unsigned short* w2ws = (unsigned short*)((char*)d_ws + H_BYTES);
        float*          zws  = (float*)((char*)d_ws + H_BYTES + W2B_BYTES);

        k_z<<<dim3(M_TOT / 256), dim3(256), 0, stream>>>(x, theta, zws);
        k_h<<<dim3(M_TOT / 128, K_TOT / 128), dim3(256), 0, stream>>>(zws, W1, hws);
        k_w2<<<dim3((N_TOT * K_TOT / 8) / 256), dim3(256), 0, stream>>>(W2, w2ws);
        k_gemm<<<dim3(M_TOT / BM, N_TOT / BN), dim3(256), 0, stream>>>(hws, w2ws, out);
    } else {
        qffn_fused<<<dim3(M_TOT / BM, N_TOT / BN), dim3(256), 0, stream>>>(x, theta, W1, W2, out);
    }
}

// Round 3
// 146.247 us; speedup vs baseline: 2.5032x; 1.1895x over previous
//
#include <hip/hip_runtime.h>
#include <hip/hip_bf16.h>
#include <math.h>

// QuantumFFN: out[m,n] = sum_k relu(sum_q cos(x[m,q])cos(theta[q]) * W1[k,q]) * W2[n,k]
// M=16384, N=1024, K=4096, Q=8.
//
// Pass 1: h (bf16) and W2 (bf16) -> d_ws, tiled [*, kt][256 rows][32 k], XOR-swizzled.
// Pass 2: 256x256 bf16 MFMA GEMM, BK=32, 4-deep LDS ring, counted vmcnt (never 0),
//         one raw s_barrier per K-tile, setprio around MFMA clusters.

using f32x4  = __attribute__((ext_vector_type(4))) float;
using bf16x8 = __attribute__((ext_vector_type(8))) short;
using i32x4  = __attribute__((ext_vector_type(4))) int;

#define M_TOT 16384
#define N_TOT 1024
#define K_TOT 4096
#define NKT   128        // K-tiles of 32
#define TILEB 16384      // 256 rows x 32 k x 2B

static const size_t H_BYTES   = (size_t)M_TOT * K_TOT * 2;   // 128 MiB
static const size_t W2B_BYTES = (size_t)N_TOT * K_TOT * 2;   //   8 MiB
static const size_t WS_NEED   = H_BYTES + W2B_BYTES;

// swizzle within a 64-byte tile row (4 slots of 16B): slot' = slot ^ ((row>>1)&3)
#define SWZ32(row, bytecol) ((bytecol) ^ ((((row) >> 1) & 3) << 4))

#define GLD16(gp, lp) __builtin_amdgcn_global_load_lds( \
    (const __attribute__((address_space(1))) unsigned int*)(const void*)(gp), \
    (__attribute__((address_space(3))) unsigned int*)(void*)(lp), 16, 0, 0)

static __device__ inline unsigned short f2bf(float f) {
    __hip_bfloat16 b = __float2bfloat16(f);
    unsigned short u;
    __builtin_memcpy(&u, &b, 2);
    return u;
}

// ---------------- pass 1a: h = relu(cos(x[:, :8])cos(theta) . W1) -> bf16 tiled ----------------
// block: 256 m-rows (bx) x 128 k (by). thread: 16 m x 8 k.
__global__ __launch_bounds__(256)
void k_h(const float* __restrict__ x, const float* __restrict__ theta,
         const float* __restrict__ W1, char* __restrict__ hws)
{
    __shared__ float sZ[256 * 8];
    __shared__ float sW[128 * 8];
    const int tid = threadIdx.x;
    const int bx  = blockIdx.x;   // m-tile (256 rows)
    const int by  = blockIdx.y;   // k-chunk (128 k)

    {   // z for this block's 256 rows (one row per thread)
        const float* xp = x + ((size_t)bx * 256 + tid) * 1024;
        f32x4 a = *reinterpret_cast<const f32x4*>(xp);
        f32x4 b = *reinterpret_cast<const f32x4*>(xp + 4);
        #pragma unroll
        for (int q = 0; q < 4; ++q) {
            sZ[tid * 8 + q]     = cosf(a[q]) * cosf(theta[q]);
            sZ[tid * 8 + 4 + q] = cosf(b[q]) * cosf(theta[q + 4]);
        }
    }
    *reinterpret_cast<f32x4*>(&sW[tid * 4]) =
        *reinterpret_cast<const f32x4*>(W1 + (size_t)by * 1024 + tid * 4);
    __syncthreads();

    const int tm = tid >> 4;     // rows tm*16..+15
    const int tk = tid & 15;     // k-cols tk*8..+7 (within 128-chunk)

    f32x4 wA[8], wB[8];
    #pragma unroll
    for (int kk = 0; kk < 8; ++kk) {
        wA[kk] = *reinterpret_cast<const f32x4*>(&sW[(tk * 8 + kk) * 8]);
        wB[kk] = *reinterpret_cast<const f32x4*>(&sW[(tk * 8 + kk) * 8 + 4]);
    }

    const int kt    = by * 4 + (tk >> 2);
    const int slotb = (tk & 3) * 16;
    char* tb = hws + ((size_t)bx * NKT + kt) * TILEB;

    #pragma unroll
    for (int i = 0; i < 16; ++i) {
        const int row = tm * 16 + i;
        f32x4 za = *reinterpret_cast<const f32x4*>(&sZ[row * 8]);
        f32x4 zb = *reinterpret_cast<const f32x4*>(&sZ[row * 8 + 4]);
        unsigned hu[8];
        #pragma unroll
        for (int kk = 0; kk < 8; ++kk) {
            float h = 0.f;
            #pragma unroll
            for (int q = 0; q < 4; ++q) {
                h = fmaf(za[q], wA[kk][q], h);
                h = fmaf(zb[q], wB[kk][q], h);
            }
            hu[kk] = (unsigned)f2bf(fmaxf(h, 0.f));
        }
        i32x4 pk;
        pk[0] = (int)(hu[0] | (hu[1] << 16));
        pk[1] = (int)(hu[2] | (hu[3] << 16));
        pk[2] = (int)(hu[4] | (hu[5] << 16));
        pk[3] = (int)(hu[6] | (hu[7] << 16));
        *reinterpret_cast<i32x4*>(tb + row * 64 + SWZ32(row, slotb)) = pk;
    }
}

// ---------------- pass 1b: W2 f32 -> bf16 tiled-swizzled ----------------
__global__ __launch_bounds__(256)
void k_w2(const float* __restrict__ W2, char* __restrict__ w2ws)
{
    const int gt = blockIdx.x * 256 + threadIdx.x;   // one 8-k unit each
    const int n  = gt >> 9;                          // 512 units per n-row
    const int k8 = gt & 511;
    const float* p = W2 + (size_t)n * K_TOT + k8 * 8;
    f32x4 a = *reinterpret_cast<const f32x4*>(p);
    f32x4 b = *reinterpret_cast<const f32x4*>(p + 4);
    i32x4 pk;
    pk[0] = (int)((unsigned)f2bf(a[0]) | ((unsigned)f2bf(a[1]) << 16));
    pk[1] = (int)((unsigned)f2bf(a[2]) | ((unsigned)f2bf(a[3]) << 16));
    pk[2] = (int)((unsigned)f2bf(b[0]) | ((unsigned)f2bf(b[1]) << 16));
    pk[3] = (int)((unsigned)f2bf(b[2]) | ((unsigned)f2bf(b[3]) << 16));
    const int nt = n >> 8, row = n & 255, kt = k8 >> 2, slotb = (k8 & 3) * 16;
    char* dst = w2ws + ((size_t)nt * NKT + kt) * TILEB + row * 64 + SWZ32(row, slotb);
    *reinterpret_cast<i32x4*>(dst) = pk;
}

// ---------------- pass 2: out = h @ W2^T ----------------
// 256x256 block tile, BK=32, 8 waves (2Mx4N, 128x64 per wave), 4-deep LDS ring.
// LDS: A buf b @ b*16384, B buf b @ 65536 + b*16384  (128 KiB total).

#define KTILE_BODY(BUF, KT, DOSTAGE)                                              \
    bf16x8 a[4], a2[4], b[4];                                                     \
    _Pragma("unroll")                                                             \
    for (int i = 0; i < 4; ++i)                                                   \
        a[i] = *reinterpret_cast<const bf16x8*>(lds + (BUF) * 16384 + aoff[i]);   \
    _Pragma("unroll")                                                             \
    for (int j = 0; j < 4; ++j)                                                   \
        b[j] = *reinterpret_cast<const bf16x8*>(lds + 65536 + (BUF) * 16384 + boff[j]); \
    if (DOSTAGE) {                                                                \
        const char* g = aT + (size_t)((KT) + 3) * TILEB;                          \
        GLD16(g + tid * 16,        lds + (((BUF) + 3) & 3) * 16384 + wave * 1024);        \
        GLD16(g + 8192 + tid * 16, lds + (((BUF) + 3) & 3) * 16384 + 8192 + wave * 1024); \
    }                                                                             \
    __builtin_amdgcn_s_setprio(1);                                                \
    _Pragma("unroll")                                                             \
    for (int i = 0; i < 4; ++i)                                                   \
        _Pragma("unroll")                                                         \
        for (int j = 0; j < 4; ++j)                                               \
            acc[i][j] = __builtin_amdgcn_mfma_f32_16x16x32_bf16(a[i], b[j], acc[i][j], 0, 0, 0); \
    __builtin_amdgcn_s_setprio(0);                                                \
    _Pragma("unroll")                                                             \
    for (int i = 0; i < 4; ++i)                                                   \
        a2[i] = *reinterpret_cast<const bf16x8*>(lds + (BUF) * 16384 + aoff[i + 4]); \
    if (DOSTAGE) {                                                                \
        const char* g = bT + (size_t)((KT) + 3) * TILEB;                          \
        GLD16(g + tid * 16,        lds + 65536 + (((BUF) + 3) & 3) * 16384 + wave * 1024);        \
        GLD16(g + 8192 + tid * 16, lds + 65536 + (((BUF) + 3) & 3) * 16384 + 8192 + wave * 1024); \
    }                                                                             \
    __builtin_amdgcn_s_setprio(1);                                                \
    _Pragma("unroll")                                                             \
    for (int i = 0; i < 4; ++i)                                                   \
        _Pragma("unroll")                                                         \
        for (int j = 0; j < 4; ++j)                                               \
            acc[i + 4][j] = __builtin_amdgcn_mfma_f32_16x16x32_bf16(a2[i], b[j], acc[i + 4][j], 0, 0, 0); \
    __builtin_amdgcn_s_setprio(0);

#define KTILE(BUF, KT, DOSTAGE, WN) do {                                          \
    KTILE_BODY(BUF, KT, DOSTAGE)                                                  \
    asm volatile("s_waitcnt vmcnt(" #WN ")" ::: "memory");                        \
    __builtin_amdgcn_sched_barrier(0);                                            \
    __builtin_amdgcn_s_barrier();                                                 \
    __builtin_amdgcn_sched_barrier(0);                                            \
} while (0)

#define KTILE_LAST(BUF, KT) do { KTILE_BODY(BUF, KT, 0) } while (0)

__global__ __launch_bounds__(512, 2)
void k_gemm(const char* __restrict__ hws, const char* __restrict__ w2ws,
            float* __restrict__ out)
{
    __shared__ __align__(16) char lds[131072];

    const int tid  = threadIdx.x;
    const int lane = tid & 63;
    const int wave = tid >> 6;
    const int wm = wave >> 2;        // 0..1
    const int wn = wave & 3;         // 0..3
    const int mt = blockIdx.x;       // 0..63
    const int nt = blockIdx.y;       // 0..3

    const char* aT = hws  + (size_t)mt * NKT * TILEB;
    const char* bT = w2ws + (size_t)nt * NKT * TILEB;

    const int l16 = lane & 15;
    const int lkb = (lane >> 4) * 16;
    int aoff[8], boff[4];
    #pragma unroll
    for (int i = 0; i < 8; ++i) {
        const int row = wm * 128 + i * 16 + l16;
        aoff[i] = row * 64 + SWZ32(row, lkb);
    }
    #pragma unroll
    for (int j = 0; j < 4; ++j) {
        const int row = wn * 64 + j * 16 + l16;
        boff[j] = row * 64 + SWZ32(row, lkb);
    }

    f32x4 acc[8][4];
    #pragma unroll
    for (int i = 0; i < 8; ++i)
        #pragma unroll
        for (int j = 0; j < 4; ++j)
            acc[i][j] = {0.f, 0.f, 0.f, 0.f};

    // prologue: stage K-tiles 0,1,2 into bufs 0,1,2
    #pragma unroll
    for (int t = 0; t < 3; ++t) {
        const char* ga = aT + (size_t)t * TILEB;
        const char* gb = bT + (size_t)t * TILEB;
        GLD16(ga + tid * 16,        lds + t * 16384 + wave * 1024);
        GLD16(ga + 8192 + tid * 16, lds + t * 16384 + 8192 + wave * 1024);
        GLD16(gb + tid * 16,        lds + 65536 + t * 16384 + wave * 1024);
        GLD16(gb + 8192 + tid * 16, lds + 65536 + t * 16384 + 8192 + wave * 1024);
    }
    asm volatile("s_waitcnt vmcnt(8)" ::: "memory");   // K-tile 0 resident
    __builtin_amdgcn_sched_barrier(0);
    __builtin_amdgcn_s_barrier();
    __builtin_amdgcn_sched_barrier(0);

    #pragma unroll 1
    for (int t = 0; t < NKT - 4; t += 4) {
        KTILE(0, t,     1, 8);
        KTILE(1, t + 1, 1, 8);
        KTILE(2, t + 2, 1, 8);
        KTILE(3, t + 3, 1, 8);
    }
    KTILE(0, NKT - 4, 1, 8);     // stages K-tile 127
    KTILE(1, NKT - 3, 0, 4);
    KTILE(2, NKT - 2, 0, 0);
    KTILE_LAST(3, NKT - 1);

    const int orow0 = mt * 256 + wm * 128 + (lane >> 4) * 4;
    const int ocol0 = nt * 256 + wn * 64 + l16;
    #pragma unroll
    for (int i = 0; i < 8; ++i)
        #pragma unroll
        for (int j = 0; j < 4; ++j)
            #pragma unroll
            for (int jj = 0; jj < 4; ++jj)
                out[(size_t)(orow0 + i * 16 + jj) * N_TOT + (ocol0 + j * 16)] = acc[i][j][jj];
}

// ---------------- fallback: fused single kernel (ws too small) ----------------
__global__ __launch_bounds__(256, 3)
void qffn_fused(const float* __restrict__ x, const float* __restrict__ theta,
                const float* __restrict__ W1, const float* __restrict__ W2,
                float* __restrict__ out)
{
    __shared__ __align__(16) unsigned short sA[128 * 64];
    __shared__ __align__(16) unsigned short sB[128 * 64];

    const int tid  = threadIdx.x;
    const int lane = tid & 63;
    const int wave = tid >> 6;
    const int m0 = blockIdx.x * 128;
    const int n0 = blockIdx.y * 128;

    const int arow = tid & 127;
    float zc[8];
    {
        const float* xp = x + (size_t)(m0 + arow) * 1024;
        f32x4 x0 = *reinterpret_cast<const f32x4*>(xp);
        f32x4 x1 = *reinterpret_cast<const f32x4*>(xp + 4);
        #pragma unroll
        for (int q = 0; q < 4; ++q) {
            zc[q]     = cosf(x0[q]) * cosf(theta[q]);
            zc[q + 4] = cosf(x1[q]) * cosf(theta[q + 4]);
        }
    }

    f32x4 acc[4][4];
    #pragma unroll
    for (int i = 0; i < 4; ++i)
        #pragma unroll
        for (int j = 0; j < 4; ++j)
            acc[i][j] = {0.f, 0.f, 0.f, 0.f};

    const int wr  = (wave >> 1) * 64;
    const int wc  = (wave & 1) * 64;
    const int l16 = lane & 15;
    const int lk8 = (lane >> 4) * 8;

    for (int k0 = 0; k0 < K_TOT; k0 += 64) {
        #pragma unroll
        for (int g = 0; g < 4; ++g) {
            const int cg  = (tid >> 7) + 2 * g;
            const int cgu = __builtin_amdgcn_readfirstlane(cg);
            const float* w1p = W1 + (size_t)(k0 + cgu * 8) * 8;
            i32x4 pk;
            #pragma unroll
            for (int p = 0; p < 4; ++p) {
                float h0 = 0.f, h1 = 0.f;
                #pragma unroll
                for (int q = 0; q < 8; ++q) {
                    h0 = fmaf(zc[q], w1p[(2 * p) * 8 + q], h0);
                    h1 = fmaf(zc[q], w1p[(2 * p + 1) * 8 + q], h1);
                }
                pk[p] = (int)(((unsigned)f2bf(fmaxf(h0, 0.f))) |
                              (((unsigned)f2bf(fmaxf(h1, 0.f))) << 16));
            }
            const int off = (arow * 64 + cg * 8) ^ ((arow & 7) << 3);
            *reinterpret_cast<i32x4*>(&sA[off]) = pk;
        }
        {
            const int fi = tid & 15;
            const int rb = tid >> 4;
            #pragma unroll
            for (int r = 0; r < 8; ++r) {
                const int row = rb + r * 16;
                f32x4 v = *(reinterpret_cast<const f32x4*>(W2 + (size_t)(n0 + row) * K_TOT + k0) + fi);
                unsigned p0 = (unsigned)f2bf(v[0]) | ((unsigned)f2bf(v[1]) << 16);
                unsigned p1 = (unsigned)f2bf(v[2]) | ((unsigned)f2bf(v[3]) << 16);
                const int off = (row * 64 + fi * 4) ^ ((row & 7) << 3);
                *reinterpret_cast<unsigned*>(&sB[off])     = p0;
                *reinterpret_cast<unsigned*>(&sB[off + 2]) = p1;
            }
        }
        __syncthreads();

        #pragma unroll
        for (int s = 0; s < 2; ++s) {
            bf16x8 af[4], bfr[4];
            #pragma unroll
            for (int i = 0; i < 4; ++i) {
                const int row = wr + i * 16 + l16;
                const int off = (row * 64 + s * 32 + lk8) ^ ((row & 7) << 3);
                af[i] = *reinterpret_cast<const bf16x8*>(&sA[off]);
            }
            #pragma unroll
            for (int j = 0; j < 4; ++j) {
                const int row = wc + j * 16 + l16;
                const int off = (row * 64 + s * 32 + lk8) ^ ((row & 7) << 3);
                bfr[j] = *reinterpret_cast<const bf16x8*>(&sB[off]);
            }
            #pragma unroll
            for (int i = 0; i < 4; ++i)
                #pragma unroll
                for (int j = 0; j < 4; ++j)
                    acc[i][j] = __builtin_amdgcn_mfma_f32_16x16x32_bf16(af[i], bfr[j], acc[i][j], 0, 0, 0);
        }
        __syncthreads();
    }

    const int orow0 = m0 + wr + (lane >> 4) * 4;
    const int ocol0 = n0 + wc + l16;
    #pragma unroll
    for (int i = 0; i < 4; ++i)
        #pragma unroll
        for (int j = 0; j < 4; ++j)
            #pragma unroll
            for (int jj = 0; jj < 4; ++jj)
                out[(size_t)(orow0 + i * 16 + jj) * N_TOT + (ocol0 + j * 16)] = acc[i][j][jj];
}

extern "C" void kernel_launch(void* const* d_in, const int* in_sizes, int n_in,
                              void* d_out, int out_size, void* d_ws, size_t ws_size,
                              hipStream_t stream) {
    const float* x     = (const float*)d_in[0];
    const float* theta = (const float*)d_in[1];
    const float* W1    = (const float*)d_in[2];
    const float* W2    = (const float*)d_in[3];
    float* out = (float*)d_out;

    if (ws_size >= WS_NEED) {
        char* hws  = (char*)d_ws;
        char* w2ws = (char*)d_ws + H_BYTES;

        k_h<<<dim3(M_TOT / 256, K_TOT / 128), dim3(256), 0, stream>>>(x, theta, W1, hws);
        k_w2<<<dim3((N_TOT * K_TOT / 8) / 256), dim3(256), 0, stream>>>(W2, w2ws);
        k_gemm<<<dim3(M_TOT / 256, N_TOT / 256), dim3(512), 0, stream>>>(hws, w2ws, out);
    } else {
        qffn_fused<<<dim3(M_TOT / 128, N_TOT / 128), dim3(256), 0, stream>>>(x, theta, W1, W2, out);
    }
}